// Round 9
// baseline (739.096 us; speedup 1.0000x reference)
//
#include <hip/hip_runtime.h>
#include <hip/hip_bf16.h>

typedef __bf16 bf16_t;
typedef bf16_t bf16x8 __attribute__((ext_vector_type(8)));
typedef bf16_t bf16x4 __attribute__((ext_vector_type(4)));
typedef bf16_t bf16x2v __attribute__((ext_vector_type(2)));
typedef float f32x4 __attribute__((ext_vector_type(4)));
typedef float f32x2 __attribute__((ext_vector_type(2)));

#define DEG_CAP 64     // padded-CSR stride; P(deg>=64)~1e-21/node at Poisson(16)
#define BKT_SHIFT 7    // 128 nodes per bucket (782 buckets)
#define BKT_NODES 128
#define BKT_CAP 3328   // records per bucket; mean 2048, sigma ~45 -> 28-sigma margin
#define EPT 16         // edges per thread in pass A
#define LDW 136        // LDS tile row stride (128 + 8 bf16 pad)

__device__ __forceinline__ void cvt4(const float* __restrict__ s, bf16_t* __restrict__ d, int i) {
    f32x4 v = ((const f32x4*)s)[i];
    bf16x4 o;
#pragma unroll
    for (int j = 0; j < 4; ++j) o[j] = (bf16_t)v[j];
    ((bf16x4*)d)[i] = o;
}

// fused setup: 4 weight cvts + zero bucket counters + zero pad-row of each
// Yt slice (8 slices x 16 bf16 = 64 ints; pad row index = srow-1)
__global__ void setup_k(const float* W1f, bf16_t* W1b,
                        const float* W2f, bf16_t* W2b,
                        const float* fW1f, bf16_t* fW1b,
                        const float* fW2f, bf16_t* fW2b,
                        int* gbcnt, int NB, int* yzero, int srow) {
    int i = blockIdx.x * blockDim.x + threadIdx.x;
    if (i < 4096) { cvt4(W1f, W1b, i); return; }
    i -= 4096;
    if (i < 4096) { cvt4(W2f, W2b, i); return; }
    i -= 4096;
    if (i < 4096) { cvt4(fW1f, fW1b, i); return; }
    i -= 4096;
    if (i < 2048) { cvt4(fW2f, fW2b, i); return; }
    i -= 2048;
    if (i < NB) { gbcnt[i] = 0; return; }
    i -= NB;
    if (i < 64) {
        int sl = i >> 3, d = i & 7;
        yzero[((size_t)sl * srow + (srow - 1)) * 8 + d] = 0;
    }
}

// ---------------- pass A: bucket edges by target (dense appends, no per-edge
// global atomics). Record = (r << 7) | (c & 127); bucket = c >> 7. -------------
__global__ __launch_bounds__(256) void bucket_scatter_k(const int* __restrict__ ei,
                                                        int* __restrict__ gbcnt,
                                                        unsigned* __restrict__ grec,
                                                        int E, int N) {
    __shared__ int hist[1024];
    __shared__ int base[1024];
    const int tid = threadIdx.x;
    const int NB = (N + BKT_NODES - 1) >> BKT_SHIFT;
    for (int i = tid; i < NB; i += 256) hist[i] = 0;
    __syncthreads();

    const int wave = tid >> 6, lane = tid & 63;
    const int e0 = blockIdx.x * (256 * EPT) + wave * (64 * EPT) + lane;
    // int32 vs int64-on-device hedge
    const bool i64 = (ei[1] == 0) & (ei[3] == 0) & (ei[5] == 0) & (ei[7] == 0);

    unsigned rec[EPT];
    int lof[EPT];
    int bk[EPT];
#pragma unroll
    for (int j = 0; j < EPT; ++j) {
        int e = e0 + j * 64;            // coalesced: consecutive lanes, consecutive edges
        bk[j] = -1;
        if (e < E) {
            int r, c;
            if (i64) { r = ei[2 * e]; c = ei[2 * E + 2 * e]; }
            else     { r = ei[e];     c = ei[E + e]; }
            r = ((unsigned)r < (unsigned)N) ? r : 0;
            c = ((unsigned)c < (unsigned)N) ? c : 0;
            int b = c >> BKT_SHIFT;
            rec[j] = ((unsigned)r << BKT_SHIFT) | (unsigned)(c & (BKT_NODES - 1));
            bk[j] = b;
            lof[j] = atomicAdd(&hist[b], 1);   // LDS atomic
        }
    }
    __syncthreads();
    for (int i = tid; i < NB; i += 256)
        base[i] = hist[i] ? atomicAdd(&gbcnt[i], hist[i]) : 0;  // 1 global atomic / bucket / block
    __syncthreads();
#pragma unroll
    for (int j = 0; j < EPT; ++j) {
        if (bk[j] >= 0) {
            int pos = base[bk[j]] + lof[j];
            if (pos < BKT_CAP)                  // guard: never corrupt
                grec[(size_t)bk[j] * BKT_CAP + pos] = rec[j];
        }
    }
}

// ---------------- pass B: one block per bucket (782 blocks); LDS-atomic
// placement into the bucket's private srcx region; pad each slab to >=16 and
// to the next multiple of 16 with index N (zero row) -> gather guard-free.
__global__ __launch_bounds__(256) void bucket_place_k(const int* __restrict__ gbcnt,
                                                      const unsigned* __restrict__ grec,
                                                      int* __restrict__ cnt,
                                                      int* __restrict__ srcx, int N) {
    __shared__ int lcnt[BKT_NODES];
    const int b = blockIdx.x, tid = threadIdx.x;
    if (tid < BKT_NODES) lcnt[tid] = 0;
    __syncthreads();
    int ne = gbcnt[b];
    if (ne > BKT_CAP) ne = BKT_CAP;
    const unsigned* rp = grec + (size_t)b * BKT_CAP;
    const int node0 = b << BKT_SHIFT;
    for (int i = tid; i < ne; i += 256) {
        unsigned rec = rp[i];
        int cl = rec & (BKT_NODES - 1);
        int r  = rec >> BKT_SHIFT;
        int p = atomicAdd(&lcnt[cl], 1);        // LDS atomic
        if (p < DEG_CAP) srcx[(size_t)(node0 + cl) * DEG_CAP + p] = r;
    }
    __syncthreads();
    int node = node0 + tid;
    if (tid < BKT_NODES && node < N) {
        int c = lcnt[tid];
        cnt[node] = c;                           // true count (for dinv)
        int cc = (c < DEG_CAP) ? c : DEG_CAP;
        int pe = (cc + 15) & ~15;
        if (pe < 16) pe = 16;                    // batch 0 always valid
        if (pe > DEG_CAP) pe = DEG_CAP;
        int* s = srcx + (size_t)node * DEG_CAP;
        for (int p = cc; p < pe; ++p) s[p] = N;  // pad -> zero row
    }
}

// ---------------- sliced gather: Yt layout [slice][srow][16 feats]. Block b
// handles slice s = b&7 (round-robin -> XCD s; slice = 3.2 MB, L2-resident)
// for 4 nodes (1 node/wave). Wave = 8 source-groups x 8 feat-lanes; each lane
// loads one dword (2 bf16) of its group's source row; shfl_xor(8/16/32) reduce.
// out/out2 keep the normal [node][128] layout.
template <int RELU, int WF32>
__global__ __launch_bounds__(256) void gather_s(const bf16_t* __restrict__ Yt,
                                                const int* __restrict__ cnt,
                                                const int* __restrict__ srcx,
                                                const float* __restrict__ bias,
                                                bf16_t* __restrict__ out,
                                                float* __restrict__ out2,
                                                int n, int srow) {
    const int s = blockIdx.x & 7;                 // slice -> XCD (perf heuristic only)
    const int node = (blockIdx.x >> 3) * 4 + (threadIdx.x >> 6);
    if (node >= n) return;
    const int lane = threadIdx.x & 63;
    const int g = lane >> 3;                      // source group 0..7
    const int fl = lane & 7;                      // feature dword 0..7
    const bf16_t* Ys = Yt + (size_t)s * srow * 16;
    const int* sl = srcx + (size_t)node * DEG_CAP;

    // issue self dword, batch-0 srcx, and cnt concurrently (no dependence)
    unsigned selfd = *(const unsigned*)(Ys + (size_t)node * 16 + fl * 2);
    int s0 = sl[g];                               // slab >=16 slots, always valid
    int c = cnt[node];
    float di = rsqrtf((float)c + 1.0f);
    int cg = (c < DEG_CAP) ? c : DEG_CAP;
    int nb = (cg + 7) & ~7;                       // pads (-> zero row N) absorb tail

    unsigned d0 = *(const unsigned*)(Ys + (size_t)s0 * 16 + fl * 2);
    float a0 = __uint_as_float(d0 << 16);
    float a1 = __uint_as_float(d0 & 0xFFFF0000u);
    for (int e = 8; e < nb; e += 8) {
        int sv = sl[e + g];
        unsigned d = *(const unsigned*)(Ys + (size_t)sv * 16 + fl * 2);
        a0 += __uint_as_float(d << 16);
        a1 += __uint_as_float(d & 0xFFFF0000u);
    }
    a0 += __shfl_xor(a0, 8);  a1 += __shfl_xor(a1, 8);
    a0 += __shfl_xor(a0, 16); a1 += __shfl_xor(a1, 16);
    a0 += __shfl_xor(a0, 32); a1 += __shfl_xor(a1, 32);
    a0 += __uint_as_float(selfd << 16);
    a1 += __uint_as_float(selfd & 0xFFFF0000u);

    float2 bb = *(const float2*)(bias + s * 16 + fl * 2);
    float v0 = di * a0 + bb.x;
    float v1 = di * a1 + bb.y;
    if (RELU) { v0 = fmaxf(v0, 0.f); v1 = fmaxf(v1, 0.f); }

    if (g == 0) {
        bf16x2v o;
        o[0] = (bf16_t)v0;
        o[1] = (bf16_t)v1;
        *(bf16x2v*)(out + (size_t)node * 128 + s * 16 + fl * 2) = o;
    }
    if (WF32 && g == 1) {
        float2 w = {v0, v1};
        *(float2*)(out2 + (size_t)node * 128 + s * 16 + fl * 2) = w;
    }
}

// ---------------- MFMA GEMM (mix layers): out = bf16(rsqrt(cnt+1)*(A@W^T)) --
// AF32: A is f32 (converted to bf16 fragments in-register). Output written
// SLICE-MAJOR: out[((size_t)n * srow + row) * 16 + l16] (n-tile = 16-feat slice).
// Layout (HW-verified): A: m=lane&15,k=quad*8+j; B: n=lane&15,k=quad*8+j;
// C/D: col=lane&15,row=quad*4+reg.
template <int OC, int MT, int AF32>
__global__ __launch_bounds__(256) void gemm_k(const void* __restrict__ Av,
                                              const bf16_t* __restrict__ W,
                                              const int* __restrict__ cnt,
                                              bf16_t* __restrict__ out, int nrows,
                                              int srow) {
    const int lane = threadIdx.x & 63;
    const int wave = threadIdx.x >> 6;
    const int l16 = lane & 15;
    const int quad = lane >> 4;
    constexpr int NT = OC / 16;
    const int ntiles = (nrows + 15) >> 4;
    const int t0 = (blockIdx.x * 4 + wave) * MT;
    if (t0 >= ntiles) return;

    f32x4 acc[MT][NT];
#pragma unroll
    for (int mt = 0; mt < MT; ++mt)
#pragma unroll
        for (int n = 0; n < NT; ++n) acc[mt][n] = (f32x4){0.f, 0.f, 0.f, 0.f};

    const bf16_t* arow[MT];
    const float* afrow[MT];
#pragma unroll
    for (int mt = 0; mt < MT; ++mt) {
        int r = t0 * 16 + mt * 16 + l16;
        if (r > nrows - 1) r = nrows - 1;
        if (AF32) afrow[mt] = (const float*)Av + (size_t)r * 128 + quad * 8;
        else      arow[mt]  = (const bf16_t*)Av + (size_t)r * 128 + quad * 8;
    }
    const bf16_t* wrow = W + (size_t)l16 * 128 + quad * 8;

#pragma unroll
    for (int kt = 0; kt < 4; ++kt) {
        bf16x8 a[MT];
#pragma unroll
        for (int mt = 0; mt < MT; ++mt) {
            if (AF32) {
                f32x4 lo = *(const f32x4*)(afrow[mt] + kt * 32);
                f32x4 hi = *(const f32x4*)(afrow[mt] + kt * 32 + 4);
#pragma unroll
                for (int j = 0; j < 4; ++j) {
                    a[mt][j] = (bf16_t)lo[j];
                    a[mt][j + 4] = (bf16_t)hi[j];
                }
            } else {
                a[mt] = *(const bf16x8*)(arow[mt] + kt * 32);
            }
        }
#pragma unroll
        for (int n = 0; n < NT; ++n) {
            bf16x8 b = *(const bf16x8*)(wrow + (size_t)n * 2048 + kt * 32);
#pragma unroll
            for (int mt = 0; mt < MT; ++mt)
                acc[mt][n] = __builtin_amdgcn_mfma_f32_16x16x32_bf16(a[mt], b, acc[mt][n], 0, 0, 0);
        }
    }

#pragma unroll
    for (int mt = 0; mt < MT; ++mt) {
        int m0 = (t0 + mt) * 16;
        if (m0 >= nrows) break;
#pragma unroll
        for (int r = 0; r < 4; ++r) {
            int row = m0 + quad * 4 + r;
            if (row < nrows) {
                float sc = rsqrtf((float)cnt[row] + 1.0f);
#pragma unroll
                for (int n = 0; n < NT; ++n)
                    out[((size_t)n * srow + row) * 16 + l16] = (bf16_t)(sc * acc[mt][n][r]);
            }
        }
    }
}

// ---------------- fused head: H = elu(zs@fcW1^T+b1); res = log_softmax(H@fcW2^T+b2)
// Row-local chain; one 16-row tile per wave. H tile round-trips through padded
// LDS to convert C-layout (col=l16,row=quad*4+r) -> A-fragment (m=l16,k=quad*8+j).
__global__ __launch_bounds__(256) void head_k(const bf16_t* __restrict__ A,
                                              const bf16_t* __restrict__ W1,
                                              const float* __restrict__ b1,
                                              const bf16_t* __restrict__ W2,
                                              const float* __restrict__ b2,
                                              float* __restrict__ outf, int nrows) {
    __shared__ bf16_t hl[4][16 * LDW];
    const int lane = threadIdx.x & 63;
    const int wave = threadIdx.x >> 6;
    const int l16 = lane & 15;
    const int quad = lane >> 4;
    const int ntiles = (nrows + 15) >> 4;
    int t = blockIdx.x * 4 + wave;
    const bool live = t < ntiles;
    if (!live) t = ntiles - 1;                 // all waves reach __syncthreads
    const int m0 = t * 16;

    // ---- stage 1: H = elu(A@W1^T + b1), OC=128 ----
    f32x4 acc[8];
#pragma unroll
    for (int n = 0; n < 8; ++n) acc[n] = (f32x4){0.f, 0.f, 0.f, 0.f};
    int r0 = m0 + l16;
    if (r0 > nrows - 1) r0 = nrows - 1;
    const bf16_t* arow = A + (size_t)r0 * 128 + quad * 8;
    const bf16_t* wrow = W1 + (size_t)l16 * 128 + quad * 8;
#pragma unroll
    for (int kt = 0; kt < 4; ++kt) {
        bf16x8 a = *(const bf16x8*)(arow + kt * 32);
#pragma unroll
        for (int n = 0; n < 8; ++n) {
            bf16x8 b = *(const bf16x8*)(wrow + (size_t)n * 2048 + kt * 32);
            acc[n] = __builtin_amdgcn_mfma_f32_16x16x32_bf16(a, b, acc[n], 0, 0, 0);
        }
    }
    // elu + store H tile to LDS (C layout: col=n*16+l16, row=quad*4+r)
    bf16_t* hw = hl[wave];
#pragma unroll
    for (int n = 0; n < 8; ++n) {
        float bb = b1[n * 16 + l16];
#pragma unroll
        for (int r = 0; r < 4; ++r) {
            float v = acc[n][r] + bb;
            v = (v > 0.0f) ? v : (expf(v) - 1.0f);   // elu alpha=1
            hw[(quad * 4 + r) * LDW + n * 16 + l16] = (bf16_t)v;
        }
    }
    __syncthreads();

    // ---- stage 2: res = log_softmax(H@W2^T + b2), OC=64 ----
    f32x4 acc2[4];
#pragma unroll
    for (int n = 0; n < 4; ++n) acc2[n] = (f32x4){0.f, 0.f, 0.f, 0.f};
    const bf16_t* hrow = hw + l16 * LDW + quad * 8;      // A-frag: m=l16, k=quad*8+j
    const bf16_t* wrow2 = W2 + (size_t)l16 * 128 + quad * 8;
#pragma unroll
    for (int kt = 0; kt < 4; ++kt) {
        bf16x8 a = *(const bf16x8*)(hrow + kt * 32);
#pragma unroll
        for (int n = 0; n < 4; ++n) {
            bf16x8 b = *(const bf16x8*)(wrow2 + (size_t)n * 2048 + kt * 32);
            acc2[n] = __builtin_amdgcn_mfma_f32_16x16x32_bf16(a, b, acc2[n], 0, 0, 0);
        }
    }
#pragma unroll
    for (int r = 0; r < 4; ++r) {
        float v[4];
#pragma unroll
        for (int n = 0; n < 4; ++n) v[n] = acc2[n][r] + b2[n * 16 + l16];
        float mx = v[0];
#pragma unroll
        for (int n = 1; n < 4; ++n) mx = fmaxf(mx, v[n]);
#pragma unroll
        for (int m = 8; m >= 1; m >>= 1) mx = fmaxf(mx, __shfl_xor(mx, m));
        float s = 0.0f;
#pragma unroll
        for (int n = 0; n < 4; ++n) s += expf(v[n] - mx);
#pragma unroll
        for (int m = 8; m >= 1; m >>= 1) s += __shfl_xor(s, m);
        float lse = mx + logf(s);
        int row = m0 + quad * 4 + r;
        if (live && row < nrows)
#pragma unroll
            for (int n = 0; n < 4; ++n)
                outf[(size_t)row * 64 + n * 16 + l16] = v[n] - lse;
    }
}

// ---------------- launch ----------------
extern "C" void kernel_launch(void* const* d_in, const int* in_sizes, int n_in,
                              void* d_out, int out_size, void* d_ws, size_t ws_size,
                              hipStream_t stream) {
    const float* xf    = (const float*)d_in[0];
    const int*   ei    = (const int*)d_in[1];
    const float* W1f   = (const float*)d_in[2];
    const float* b1f   = (const float*)d_in[3];
    const float* W2f   = (const float*)d_in[4];
    const float* b2f   = (const float*)d_in[5];
    const float* fcW1f = (const float*)d_in[6];
    const float* fcb1f = (const float*)d_in[7];
    const float* fcW2f = (const float*)d_in[8];
    const float* fcb2f = (const float*)d_in[9];

    const int N = in_sizes[0] / 128;
    const int E = in_sizes[1] / 2;
    const int NB = (N + BKT_NODES - 1) >> BKT_SHIFT;
    const int srow = N + 1;                            // slice row count (+zero pad row)

    float* zs_out  = (float*)d_out;                    // N*128 f32
    float* res_out = (float*)d_out + (size_t)N * 128;  // N*64  f32

    char* ws = (char*)d_ws;
    size_t o = 0;
    auto carve = [&](size_t bytes) { void* p = ws + o; o = (o + bytes + 255) & ~255UL; return p; };
    int*      cnt   = (int*)carve((size_t)N * 4);
    int*      srcx  = (int*)carve((size_t)N * DEG_CAP * 4);      // padded CSR, 25.6 MB
    bf16_t*   Xbf   = (bf16_t*)carve((size_t)N * 128 * 2);       // A2 / zs (bf16, row-major)
    bf16_t*   Ybf   = (bf16_t*)carve((size_t)srow * 128 * 2);    // Yt: 8 slices x srow x 16
    bf16_t*   W1b   = (bf16_t*)carve(128 * 128 * 2);
    bf16_t*   W2b   = (bf16_t*)carve(128 * 128 * 2);
    bf16_t*   fW1b  = (bf16_t*)carve(128 * 128 * 2);
    bf16_t*   fW2b  = (bf16_t*)carve(64 * 128 * 2);
    unsigned* grec  = (unsigned*)carve((size_t)NB * BKT_CAP * 4); // ~10.4 MB
    int*      gbcnt = (int*)carve((size_t)NB * 4);

    const int B = 256;
    const int ntiles = (N + 15) / 16;
    const int gblocks = (ntiles + 7) / 8;       // 4 waves * MT=2 tiles
    const int hblocks = (ntiles + 3) / 4;       // 4 waves * 1 tile
    const int sblocks = 8 * ((N + 3) / 4);      // sliced gather: slice = b&7
    const int nsetup = 4096 * 3 + 2048 + NB + 64;
    const int ablocks = (E + 256 * EPT - 1) / (256 * EPT);

    setup_k<<<(nsetup + B - 1) / B, B, 0, stream>>>(W1f, W1b, W2f, W2b,
                                                    fcW1f, fW1b, fcW2f, fW2b, gbcnt, NB,
                                                    (int*)Ybf, srow);
    bucket_scatter_k<<<ablocks, B, 0, stream>>>(ei, gbcnt, grec, E, N);
    bucket_place_k<<<NB, B, 0, stream>>>(gbcnt, grec, cnt, srcx, N);

    // layer 1: Ys1 = dinv*(X@W1^T) (X f32) -> Yt ; A2 = relu(dinv*agg+b1) -> Xbf
    gemm_k<128, 2, 1><<<gblocks, B, 0, stream>>>((const void*)xf, W1b, cnt, Ybf, N, srow);
    gather_s<1, 0><<<sblocks, B, 0, stream>>>(Ybf, cnt, srcx, b1f, Xbf, nullptr, N, srow);

    // layer 2: Ys2 = dinv*(A2@W2^T) -> Yt ; zs = dinv*agg+b2 -> bf16 Xbf + f32 d_out
    gemm_k<128, 2, 0><<<gblocks, B, 0, stream>>>((const void*)Xbf, W2b, cnt, Ybf, N, srow);
    gather_s<0, 1><<<sblocks, B, 0, stream>>>(Ybf, cnt, srcx, b2f, Xbf, zs_out, N, srow);

    // fused head: H = elu(zs@fcW1^T+fcb1) in LDS ; res = log_softmax(H@fcW2^T+fcb2)
    head_k<<<hblocks, B, 0, stream>>>(Xbf, fW1b, fcb1f, fW2b, fcb2f, res_out, N);
}

// Round 10
// 390.993 us; speedup vs baseline: 1.8903x; 1.8903x over previous
//
#include <hip/hip_runtime.h>
#include <hip/hip_bf16.h>

typedef __bf16 bf16_t;
typedef bf16_t bf16x8 __attribute__((ext_vector_type(8)));
typedef bf16_t bf16x4 __attribute__((ext_vector_type(4)));
typedef float f32x4 __attribute__((ext_vector_type(4)));
typedef float f32x2 __attribute__((ext_vector_type(2)));

#define DEG_CAP 64     // padded-CSR stride; P(deg>=64)~1e-21/node at Poisson(16)
#define BKT_SHIFT 7    // 128 nodes per bucket (782 buckets)
#define BKT_NODES 128
#define BKT_CAP 3328   // records per bucket; mean 2048, sigma ~45 -> 28-sigma margin
#define EPT 16         // edges per thread in pass A
#define LDW 136        // LDS tile row stride (128 + 8 bf16 pad)

__device__ __forceinline__ void cvt4(const float* __restrict__ s, bf16_t* __restrict__ d, int i) {
    f32x4 v = ((const f32x4*)s)[i];
    bf16x4 o;
#pragma unroll
    for (int j = 0; j < 4; ++j) o[j] = (bf16_t)v[j];
    ((bf16x4*)d)[i] = o;
}

// fused setup: 4 weight cvts + zero bucket counters + zero pad-row of Ybf
__global__ void setup_k(const float* W1f, bf16_t* W1b,
                        const float* W2f, bf16_t* W2b,
                        const float* fW1f, bf16_t* fW1b,
                        const float* fW2f, bf16_t* fW2b,
                        int* gbcnt, int NB, int* yzero) {
    int i = blockIdx.x * blockDim.x + threadIdx.x;
    if (i < 4096) { cvt4(W1f, W1b, i); return; }
    i -= 4096;
    if (i < 4096) { cvt4(W2f, W2b, i); return; }
    i -= 4096;
    if (i < 4096) { cvt4(fW1f, fW1b, i); return; }
    i -= 4096;
    if (i < 2048) { cvt4(fW2f, fW2b, i); return; }
    i -= 2048;
    if (i < NB) { gbcnt[i] = 0; return; }
    i -= NB;
    if (i < 64) yzero[i] = 0;   // zero row N of Ybf (128 bf16 = 64 ints)
}

// ---------------- pass A: bucket edges by target (dense appends, no per-edge
// global atomics). Record = (r << 7) | (c & 127); bucket = c >> 7. -------------
__global__ __launch_bounds__(256) void bucket_scatter_k(const int* __restrict__ ei,
                                                        int* __restrict__ gbcnt,
                                                        unsigned* __restrict__ grec,
                                                        int E, int N) {
    __shared__ int hist[1024];
    __shared__ int base[1024];
    const int tid = threadIdx.x;
    const int NB = (N + BKT_NODES - 1) >> BKT_SHIFT;
    for (int i = tid; i < NB; i += 256) hist[i] = 0;
    __syncthreads();

    const int wave = tid >> 6, lane = tid & 63;
    const int e0 = blockIdx.x * (256 * EPT) + wave * (64 * EPT) + lane;
    // int32 vs int64-on-device hedge
    const bool i64 = (ei[1] == 0) & (ei[3] == 0) & (ei[5] == 0) & (ei[7] == 0);

    unsigned rec[EPT];
    int lof[EPT];
    int bk[EPT];
#pragma unroll
    for (int j = 0; j < EPT; ++j) {
        int e = e0 + j * 64;            // coalesced: consecutive lanes, consecutive edges
        bk[j] = -1;
        if (e < E) {
            int r, c;
            if (i64) { r = ei[2 * e]; c = ei[2 * E + 2 * e]; }
            else     { r = ei[e];     c = ei[E + e]; }
            r = ((unsigned)r < (unsigned)N) ? r : 0;
            c = ((unsigned)c < (unsigned)N) ? c : 0;
            int b = c >> BKT_SHIFT;
            rec[j] = ((unsigned)r << BKT_SHIFT) | (unsigned)(c & (BKT_NODES - 1));
            bk[j] = b;
            lof[j] = atomicAdd(&hist[b], 1);   // LDS atomic
        }
    }
    __syncthreads();
    for (int i = tid; i < NB; i += 256)
        base[i] = hist[i] ? atomicAdd(&gbcnt[i], hist[i]) : 0;  // 1 global atomic / bucket / block
    __syncthreads();
#pragma unroll
    for (int j = 0; j < EPT; ++j) {
        if (bk[j] >= 0) {
            int pos = base[bk[j]] + lof[j];
            if (pos < BKT_CAP)                  // guard: never corrupt
                grec[(size_t)bk[j] * BKT_CAP + pos] = rec[j];
        }
    }
}

// ---------------- pass B: one block per bucket (782 blocks); LDS-atomic
// placement into the bucket's private srcx region; pad each slab to >=16 and
// to the next multiple of 16 with index N (zero row) -> gather guard-free.
__global__ __launch_bounds__(256) void bucket_place_k(const int* __restrict__ gbcnt,
                                                      const unsigned* __restrict__ grec,
                                                      int* __restrict__ cnt,
                                                      int* __restrict__ srcx, int N) {
    __shared__ int lcnt[BKT_NODES];
    const int b = blockIdx.x, tid = threadIdx.x;
    if (tid < BKT_NODES) lcnt[tid] = 0;
    __syncthreads();
    int ne = gbcnt[b];
    if (ne > BKT_CAP) ne = BKT_CAP;
    const unsigned* rp = grec + (size_t)b * BKT_CAP;
    const int node0 = b << BKT_SHIFT;
    for (int i = tid; i < ne; i += 256) {
        unsigned rec = rp[i];
        int cl = rec & (BKT_NODES - 1);
        int r  = rec >> BKT_SHIFT;
        int p = atomicAdd(&lcnt[cl], 1);        // LDS atomic
        if (p < DEG_CAP) srcx[(size_t)(node0 + cl) * DEG_CAP + p] = r;
    }
    __syncthreads();
    int node = node0 + tid;
    if (tid < BKT_NODES && node < N) {
        int c = lcnt[tid];
        cnt[node] = c;                           // true count (for dinv)
        int cc = (c < DEG_CAP) ? c : DEG_CAP;
        int pe = (cc + 15) & ~15;
        if (pe < 16) pe = 16;                    // batch 0 always valid
        if (pe > DEG_CAP) pe = DEG_CAP;
        int* s = srcx + (size_t)node * DEG_CAP;
        for (int p = cc; p < pe; ++p) s[p] = N;  // pad -> zero row
    }
}

// ---------------- gather: T = Ys[i] + sum Ys[src]; out = act(dinv*T + bias) --
// One wave/node. 4 lane-quads each cover one source row per dwordx4. Slabs
// padded to >=16 / x16 -> batch 0 guard-free. MLP: batch-1 srcx AND its 4 row
// loads are issued BEFORE batch-0 accumulation (speculative within the 64-slot
// slab; pads hit the zero row) so deg 17..32 nodes overlap both misses.
// Accumulation order batch0 -> batch1 preserved -> bitwise identical.
template <int RELU, int WF32>
__global__ __launch_bounds__(256) void gather_k(const bf16_t* __restrict__ Y,
                                                const int* __restrict__ cnt,
                                                const int* __restrict__ srcx,
                                                const float* __restrict__ bias,
                                                bf16_t* __restrict__ out,
                                                float* __restrict__ out2, int n) {
    int node = blockIdx.x * 4 + (threadIdx.x >> 6);
    if (node >= n) return;
    const int lane = threadIdx.x & 63;
    const int l16 = lane & 15;
    const int quad = lane >> 4;
    const int* sl = srcx + (size_t)node * DEG_CAP + quad * 4;
    const bf16_t* Yl = Y + l16 * 8;              // lane's 16B column slice

    // issue batch-0 + batch-1 srcx, self row, and cnt concurrently
    int4 sq0 = *(const int4*)sl;
    int4 sq1 = *(const int4*)(sl + 16);          // speculative; within 64-slot slab
    bf16x8 ys = *(const bf16x8*)(Yl + (size_t)node * 128);
    int c = cnt[node];
    float di = rsqrtf((float)c + 1.0f);
    int cg = (c < DEG_CAP) ? c : DEG_CAP;
    int nb = (cg + 15) & ~15;

    // batch-0 rows (always valid) and batch-1 rows (speculative) issued
    // back-to-back before any accumulation -> overlapped misses.
    bf16x8 r0 = *(const bf16x8*)(Yl + (size_t)sq0.x * 128);
    bf16x8 r1 = *(const bf16x8*)(Yl + (size_t)sq0.y * 128);
    bf16x8 r2 = *(const bf16x8*)(Yl + (size_t)sq0.z * 128);
    bf16x8 r3 = *(const bf16x8*)(Yl + (size_t)sq0.w * 128);
    bf16x8 r4, r5, r6, r7;
    const bool b1v = nb > 16;                    // wave-uniform
    if (b1v) {
        r4 = *(const bf16x8*)(Yl + (size_t)sq1.x * 128);
        r5 = *(const bf16x8*)(Yl + (size_t)sq1.y * 128);
        r6 = *(const bf16x8*)(Yl + (size_t)sq1.z * 128);
        r7 = *(const bf16x8*)(Yl + (size_t)sq1.w * 128);
    }

    f32x2 acc[4];
#pragma unroll
    for (int p = 0; p < 4; ++p) acc[p] = (f32x2){0.f, 0.f};

#define ACC_REG(yv)                                                            \
    {                                                                          \
        uint4 u = *(const uint4*)&(yv);                                        \
        acc[0] += (f32x2){__uint_as_float(u.x << 16),                          \
                          __uint_as_float(u.x & 0xFFFF0000u)};                 \
        acc[1] += (f32x2){__uint_as_float(u.y << 16),                          \
                          __uint_as_float(u.y & 0xFFFF0000u)};                 \
        acc[2] += (f32x2){__uint_as_float(u.z << 16),                          \
                          __uint_as_float(u.z & 0xFFFF0000u)};                 \
        acc[3] += (f32x2){__uint_as_float(u.w << 16),                          \
                          __uint_as_float(u.w & 0xFFFF0000u)};                 \
    }
#define ACC_ROW(s)                                                             \
    {                                                                          \
        bf16x8 yv = *(const bf16x8*)(Yl + (size_t)(s) * 128);                  \
        ACC_REG(yv)                                                            \
    }

    ACC_REG(r0); ACC_REG(r1); ACC_REG(r2); ACC_REG(r3);
    if (b1v) {
        ACC_REG(r4); ACC_REG(r5); ACC_REG(r6); ACC_REG(r7);
        for (int e = 32; e < nb; e += 16) {
            int4 s2 = *(const int4*)(sl + e);
            ACC_ROW(s2.x); ACC_ROW(s2.y); ACC_ROW(s2.z); ACC_ROW(s2.w);
        }
    }
#undef ACC_ROW
#undef ACC_REG

    // recombine quad partials: every lane ends with full sums for feats l16*8..+7
    float a[8];
#pragma unroll
    for (int p = 0; p < 4; ++p) { a[2 * p] = acc[p][0]; a[2 * p + 1] = acc[p][1]; }
#pragma unroll
    for (int j = 0; j < 8; ++j) {
        a[j] += __shfl_xor(a[j], 16);
        a[j] += __shfl_xor(a[j], 32);
    }

    f32x4 b0 = ((const f32x4*)bias)[l16 * 2];
    f32x4 b1 = ((const f32x4*)bias)[l16 * 2 + 1];
    float v[8];
#pragma unroll
    for (int j = 0; j < 8; ++j) {
        float bb = (j < 4) ? b0[j & 3] : b1[j & 3];
        v[j] = di * ((float)ys[j] + a[j]) + bb;
        if (RELU) v[j] = fmaxf(v[j], 0.f);
    }

    if (quad == 0) {
        bf16x8 o;
#pragma unroll
        for (int j = 0; j < 8; ++j) o[j] = (bf16_t)v[j];
        *(bf16x8*)(out + (size_t)node * 128 + l16 * 8) = o;
    }
    if (WF32) {
        if (quad == 1) {
            f32x4 w = {v[0], v[1], v[2], v[3]};
            *(f32x4*)(out2 + (size_t)node * 128 + l16 * 8) = w;
        } else if (quad == 2) {
            f32x4 w = {v[4], v[5], v[6], v[7]};
            *(f32x4*)(out2 + (size_t)node * 128 + l16 * 8 + 4) = w;
        }
    }
}

// ---------------- MFMA GEMM (mix layers): out = bf16(rsqrt(cnt+1)*(A@W^T)) --
// AF32: A is f32 (converted to bf16 fragments in-register). Layout (HW-verified):
// A: m=lane&15,k=quad*8+j; B: n=lane&15,k=quad*8+j; C/D: col=lane&15,row=quad*4+reg.
template <int OC, int MT, int AF32>
__global__ __launch_bounds__(256) void gemm_k(const void* __restrict__ Av,
                                              const bf16_t* __restrict__ W,
                                              const int* __restrict__ cnt,
                                              bf16_t* __restrict__ out, int nrows) {
    const int lane = threadIdx.x & 63;
    const int wave = threadIdx.x >> 6;
    const int l16 = lane & 15;
    const int quad = lane >> 4;
    constexpr int NT = OC / 16;
    const int ntiles = (nrows + 15) >> 4;
    const int t0 = (blockIdx.x * 4 + wave) * MT;
    if (t0 >= ntiles) return;

    f32x4 acc[MT][NT];
#pragma unroll
    for (int mt = 0; mt < MT; ++mt)
#pragma unroll
        for (int n = 0; n < NT; ++n) acc[mt][n] = (f32x4){0.f, 0.f, 0.f, 0.f};

    const bf16_t* arow[MT];
    const float* afrow[MT];
#pragma unroll
    for (int mt = 0; mt < MT; ++mt) {
        int r = t0 * 16 + mt * 16 + l16;
        if (r > nrows - 1) r = nrows - 1;
        if (AF32) afrow[mt] = (const float*)Av + (size_t)r * 128 + quad * 8;
        else      arow[mt]  = (const bf16_t*)Av + (size_t)r * 128 + quad * 8;
    }
    const bf16_t* wrow = W + (size_t)l16 * 128 + quad * 8;

#pragma unroll
    for (int kt = 0; kt < 4; ++kt) {
        bf16x8 a[MT];
#pragma unroll
        for (int mt = 0; mt < MT; ++mt) {
            if (AF32) {
                f32x4 lo = *(const f32x4*)(afrow[mt] + kt * 32);
                f32x4 hi = *(const f32x4*)(afrow[mt] + kt * 32 + 4);
#pragma unroll
                for (int j = 0; j < 4; ++j) {
                    a[mt][j] = (bf16_t)lo[j];
                    a[mt][j + 4] = (bf16_t)hi[j];
                }
            } else {
                a[mt] = *(const bf16x8*)(arow[mt] + kt * 32);
            }
        }
#pragma unroll
        for (int n = 0; n < NT; ++n) {
            bf16x8 b = *(const bf16x8*)(wrow + (size_t)n * 2048 + kt * 32);
#pragma unroll
            for (int mt = 0; mt < MT; ++mt)
                acc[mt][n] = __builtin_amdgcn_mfma_f32_16x16x32_bf16(a[mt], b, acc[mt][n], 0, 0, 0);
        }
    }

#pragma unroll
    for (int mt = 0; mt < MT; ++mt) {
        int m0 = (t0 + mt) * 16;
        if (m0 >= nrows) break;
#pragma unroll
        for (int r = 0; r < 4; ++r) {
            int row = m0 + quad * 4 + r;
            if (row < nrows) {
                float sc = rsqrtf((float)cnt[row] + 1.0f);
#pragma unroll
                for (int n = 0; n < NT; ++n)
                    out[(size_t)row * OC + n * 16 + l16] = (bf16_t)(sc * acc[mt][n][r]);
            }
        }
    }
}

// ---------------- fused head: H = elu(zs@fcW1^T+b1); res = log_softmax(H@fcW2^T+b2)
// Row-local chain; one 16-row tile per wave. H tile round-trips through padded
// LDS to convert C-layout (col=l16,row=quad*4+r) -> A-fragment (m=l16,k=quad*8+j).
__global__ __launch_bounds__(256) void head_k(const bf16_t* __restrict__ A,
                                              const bf16_t* __restrict__ W1,
                                              const float* __restrict__ b1,
                                              const bf16_t* __restrict__ W2,
                                              const float* __restrict__ b2,
                                              float* __restrict__ outf, int nrows) {
    __shared__ bf16_t hl[4][16 * LDW];
    const int lane = threadIdx.x & 63;
    const int wave = threadIdx.x >> 6;
    const int l16 = lane & 15;
    const int quad = lane >> 4;
    const int ntiles = (nrows + 15) >> 4;
    int t = blockIdx.x * 4 + wave;
    const bool live = t < ntiles;
    if (!live) t = ntiles - 1;                 // all waves reach __syncthreads
    const int m0 = t * 16;

    // ---- stage 1: H = elu(A@W1^T + b1), OC=128 ----
    f32x4 acc[8];
#pragma unroll
    for (int n = 0; n < 8; ++n) acc[n] = (f32x4){0.f, 0.f, 0.f, 0.f};
    int r0 = m0 + l16;
    if (r0 > nrows - 1) r0 = nrows - 1;
    const bf16_t* arow = A + (size_t)r0 * 128 + quad * 8;
    const bf16_t* wrow = W1 + (size_t)l16 * 128 + quad * 8;
#pragma unroll
    for (int kt = 0; kt < 4; ++kt) {
        bf16x8 a = *(const bf16x8*)(arow + kt * 32);
#pragma unroll
        for (int n = 0; n < 8; ++n) {
            bf16x8 b = *(const bf16x8*)(wrow + (size_t)n * 2048 + kt * 32);
            acc[n] = __builtin_amdgcn_mfma_f32_16x16x32_bf16(a, b, acc[n], 0, 0, 0);
        }
    }
    // elu + store H tile to LDS (C layout: col=n*16+l16, row=quad*4+r)
    bf16_t* hw = hl[wave];
#pragma unroll
    for (int n = 0; n < 8; ++n) {
        float bb = b1[n * 16 + l16];
#pragma unroll
        for (int r = 0; r < 4; ++r) {
            float v = acc[n][r] + bb;
            v = (v > 0.0f) ? v : (expf(v) - 1.0f);   // elu alpha=1
            hw[(quad * 4 + r) * LDW + n * 16 + l16] = (bf16_t)v;
        }
    }
    __syncthreads();

    // ---- stage 2: res = log_softmax(H@W2^T + b2), OC=64 ----
    f32x4 acc2[4];
#pragma unroll
    for (int n = 0; n < 4; ++n) acc2[n] = (f32x4){0.f, 0.f, 0.f, 0.f};
    const bf16_t* hrow = hw + l16 * LDW + quad * 8;      // A-frag: m=l16, k=quad*8+j
    const bf16_t* wrow2 = W2 + (size_t)l16 * 128 + quad * 8;
#pragma unroll
    for (int kt = 0; kt < 4; ++kt) {
        bf16x8 a = *(const bf16x8*)(hrow + kt * 32);
#pragma unroll
        for (int n = 0; n < 4; ++n) {
            bf16x8 b = *(const bf16x8*)(wrow2 + (size_t)n * 2048 + kt * 32);
            acc2[n] = __builtin_amdgcn_mfma_f32_16x16x32_bf16(a, b, acc2[n], 0, 0, 0);
        }
    }
#pragma unroll
    for (int r = 0; r < 4; ++r) {
        float v[4];
#pragma unroll
        for (int n = 0; n < 4; ++n) v[n] = acc2[n][r] + b2[n * 16 + l16];
        float mx = v[0];
#pragma unroll
        for (int n = 1; n < 4; ++n) mx = fmaxf(mx, v[n]);
#pragma unroll
        for (int m = 8; m >= 1; m >>= 1) mx = fmaxf(mx, __shfl_xor(mx, m));
        float s = 0.0f;
#pragma unroll
        for (int n = 0; n < 4; ++n) s += expf(v[n] - mx);
#pragma unroll
        for (int m = 8; m >= 1; m >>= 1) s += __shfl_xor(s, m);
        float lse = mx + logf(s);
        int row = m0 + quad * 4 + r;
        if (live && row < nrows)
#pragma unroll
            for (int n = 0; n < 4; ++n)
                outf[(size_t)row * 64 + n * 16 + l16] = v[n] - lse;
    }
}

// ---------------- launch ----------------
extern "C" void kernel_launch(void* const* d_in, const int* in_sizes, int n_in,
                              void* d_out, int out_size, void* d_ws, size_t ws_size,
                              hipStream_t stream) {
    const float* xf    = (const float*)d_in[0];
    const int*   ei    = (const int*)d_in[1];
    const float* W1f   = (const float*)d_in[2];
    const float* b1f   = (const float*)d_in[3];
    const float* W2f   = (const float*)d_in[4];
    const float* b2f   = (const float*)d_in[5];
    const float* fcW1f = (const float*)d_in[6];
    const float* fcb1f = (const float*)d_in[7];
    const float* fcW2f = (const float*)d_in[8];
    const float* fcb2f = (const float*)d_in[9];

    const int N = in_sizes[0] / 128;
    const int E = in_sizes[1] / 2;
    const int NB = (N + BKT_NODES - 1) >> BKT_SHIFT;

    float* zs_out  = (float*)d_out;                    // N*128 f32
    float* res_out = (float*)d_out + (size_t)N * 128;  // N*64  f32

    char* ws = (char*)d_ws;
    size_t o = 0;
    auto carve = [&](size_t bytes) { void* p = ws + o; o = (o + bytes + 255) & ~255UL; return p; };
    int*      cnt   = (int*)carve((size_t)N * 4);
    int*      srcx  = (int*)carve((size_t)N * DEG_CAP * 4);      // padded CSR, 25.6 MB
    bf16_t*   Xbf   = (bf16_t*)carve((size_t)N * 128 * 2);       // A2 / zs (bf16)
    bf16_t*   Ybf   = (bf16_t*)carve((size_t)(N + 1) * 128 * 2); // +1 zero pad row
    bf16_t*   W1b   = (bf16_t*)carve(128 * 128 * 2);
    bf16_t*   W2b   = (bf16_t*)carve(128 * 128 * 2);
    bf16_t*   fW1b  = (bf16_t*)carve(128 * 128 * 2);
    bf16_t*   fW2b  = (bf16_t*)carve(64 * 128 * 2);
    unsigned* grec  = (unsigned*)carve((size_t)NB * BKT_CAP * 4); // ~10.4 MB
    int*      gbcnt = (int*)carve((size_t)NB * 4);

    const int B = 256;
    const int ntiles = (N + 15) / 16;
    const int gblocks = (ntiles + 7) / 8;       // 4 waves * MT=2 tiles
    const int hblocks = (ntiles + 3) / 4;       // 4 waves * 1 tile
    const int nodeblocks = (N + 3) / 4;         // 4 waves * 1 node
    const int nsetup = 4096 * 3 + 2048 + NB + 64;
    const int ablocks = (E + 256 * EPT - 1) / (256 * EPT);

    setup_k<<<(nsetup + B - 1) / B, B, 0, stream>>>(W1f, W1b, W2f, W2b,
                                                    fcW1f, fW1b, fcW2f, fW2b, gbcnt, NB,
                                                    (int*)(Ybf + (size_t)N * 128));
    bucket_scatter_k<<<ablocks, B, 0, stream>>>(ei, gbcnt, grec, E, N);
    bucket_place_k<<<NB, B, 0, stream>>>(gbcnt, grec, cnt, srcx, N);

    // layer 1: Ys1 = dinv*(X@W1^T) (X read as f32) ; A2 = relu(dinv*agg+b1) -> Xbf
    gemm_k<128, 2, 1><<<gblocks, B, 0, stream>>>((const void*)xf, W1b, cnt, Ybf, N);
    gather_k<1, 0><<<nodeblocks, B, 0, stream>>>(Ybf, cnt, srcx, b1f, Xbf, nullptr, N);

    // layer 2: Ys2 = dinv*(A2@W2^T) ; zs = dinv*agg(Ys2)+b2 -> bf16 Xbf + f32 d_out
    gemm_k<128, 2, 0><<<gblocks, B, 0, stream>>>((const void*)Xbf, W2b, cnt, Ybf, N);
    gather_k<0, 1><<<nodeblocks, B, 0, stream>>>(Ybf, cnt, srcx, b2f, Xbf, zs_out, N);

    // fused head: H = elu(zs@fcW1^T+fcb1) in LDS ; res = log_softmax(H@fcW2^T+fcb2)
    head_k<<<hblocks, B, 0, stream>>>(Xbf, fW1b, fcb1f, fW2b, fcb2f, res_out, N);
}